// Round 13
// baseline (258.759 us; speedup 1.0000x reference)
//
#include <hip/hip_runtime.h>
#include <math.h>

#define BB 32
#define NN 128
#define DD 64
#define EE (NN*NN)          // 16384
#define EPSI 1e-5f

typedef __attribute__((ext_vector_type(8))) short bf16x8;   // 8 bf16 (4 VGPRs)
typedef __attribute__((ext_vector_type(4))) short s16x4;    // 4 bf16 (2 VGPRs)
typedef __attribute__((ext_vector_type(4))) float f32x4;

// lgkmcnt(0)-only wait (NOT s_waitcnt 0: that drains vmcnt too -> kills the
// in-flight prefetch). sched_barrier stops hipcc hoisting past it (rule #18).
#define LGKM0() do { asm volatile("s_waitcnt lgkmcnt(0)" ::: "memory"); \
                     __builtin_amdgcn_sched_barrier(0); } while (0)

__device__ __forceinline__ short f2bf(float f) {
    union { float f; unsigned u; } v; v.f = f;
    unsigned u = v.u;
    unsigned r = (u + 0x7FFFu + ((u >> 16) & 1u)) >> 16;    // RNE
    return (short)r;
}
__device__ __forceinline__ float elu(float v) {
    return v > 0.f ? v : __expf(v) - 1.f;     // v_exp_f32 path
}

// ---------------------------------------------------------------------------
// k_node (+ folded fold): blocks [0, B*N): per (b,n) row:
//   z_h = x @ Wh^T ; PsT/PdT in MFMA C-fragment layout ; s,t scalars.
// blocks [B*N, B*N+64): fold — Mbf[d][k] = bf16(sum_o Wp[d][128+o]*We[o][k]),
//   block ff==0 also wbf[k] = bf16(sum_o Wa[128+o]*We[o][k]).
__global__ void k_node(const float* __restrict__ x, const float* __restrict__ Wh,
                       const float* __restrict__ Wp, const float* __restrict__ We,
                       const float* __restrict__ Wa,
                       float* __restrict__ zh, float* __restrict__ PsT,
                       float* __restrict__ PdT, float* __restrict__ sO,
                       float* __restrict__ tO,
                       short* __restrict__ Mbf, short* __restrict__ wbf)
{
    const int row = blockIdx.x;
    const int d = threadIdx.x;           // 0..63
    if (row >= BB*NN) {                  // ---- fold tail blocks ----
        const int ff = row - BB*NN;      // 0..63 == output row d'
        float acc = 0.f;
        for (int o = 0; o < DD; ++o)
            acc += Wp[ff*192 + 128 + o] * We[o*DD + d];
        Mbf[ff*DD + d] = f2bf(acc);
        if (ff == 0) {
            float aw = 0.f;
            for (int o = 0; o < DD; ++o)
                aw += Wa[128 + o] * We[o*DD + d];
            wbf[d] = f2bf(aw);
        }
        return;
    }
    const int b = row >> 7, n = row & 127;
    __shared__ float xr[DD];
    __shared__ float zr[DD];
    xr[d] = x[row*DD + d];
    __syncthreads();
    float acc = 0.f;
#pragma unroll
    for (int k = 0; k < DD; ++k) acc += xr[k] * Wh[d*DD + k];
    zr[d] = acc;
    zh[row*DD + d] = acc;
    __syncthreads();
    float a0 = 0.f, a1 = 0.f;
#pragma unroll
    for (int o = 0; o < DD; ++o) {
        float z = zr[o];
        a0 += Wp[d*192 + o]      * z;
        a1 += Wp[d*192 + 64 + o] * z;
    }
    const int fi = ((b >> 4)*4 + (d >> 4))*256 + (((b >> 2) & 3)*16 + (d & 15))*4 + (b & 3);
    PsT[n*2048 + fi] = a0;
    PdT[n*2048 + fi] = a1;
    float sv = zr[d] * Wa[d];
    float tv = zr[d] * Wa[64 + d];
#pragma unroll
    for (int off = 32; off; off >>= 1) {
        sv += __shfl_xor(sv, off);
        tv += __shfl_xor(tv, off);
    }
    if (d == 0) { sO[row] = sv; tO[row] = tv; }
}

// ---------------------------------------------------------------------------
// k_edge v13 = v8 body + TILES-deep cross-tile software pipeline.
//   z = edge @ M^T + Ps[b,j] + Pd[b,i] -> BN(per-e over b,d) -> ELU
//   u[b,e] = edge . w  via a 5th MFMA B-tile (col0 = w)
// 256 threads = 4 waves; block handles 4*TILES consecutive channels; in tile k
// wave wv owns channel e = e0 + 4k + wv (32 b x 64 d).
// INM==0: A fp32 (B,E,D). Tile k+1's global loads are ISSUED right after tile
//   k's fragment reads; their f2bf+ds_write (vmcnt drain) sits at the END of
//   tile k's body, so HBM latency hides under the MFMA+BN+ELU epilogue.
//   Double-buffered stage LDS. One raw s_barrier per tile (lgkm-only drain) —
//   safety: buffer parity alternates; iter-k reads of As[k&1] are ordered
//   against iter-(k+1)-tail writes to As[(k+2)&1]==As[k&1] by the iter-(k+1)
//   top barrier (LGKM0 before s_barrier drains every wave's outstanding
//   ds_reads first). Repack overlays only the wave's OWN section after LGKM0.
// INM==1: A bf16 (E,B,D) dense; afr double-buffered in registers, tile k+1's
//   loads issued before tile k's epilogue. No barriers at all.
// OUTM: 0 = fp32 (B,E,D) (d_out); 1 = bf16 (E,B,D) dense intermediate.
template <int INM, int OUTM, int TILES>
__global__ __launch_bounds__(256, 4) void k_edge(
    const void* einv,
    const short* __restrict__ Mbf,   // (D,D) bf16
    const short* __restrict__ wbf,   // (D)   bf16
    const float* __restrict__ PsT,   // (N, 2048) fragment layout
    const float* __restrict__ PdT,   // (N, 2048) fragment layout
    const float* __restrict__ ge, const float* __restrict__ be,
    void* eoutv, float* __restrict__ uout)
{
    __shared__ short As[(INM == 0) ? 2 : 1][4][32][72];   // stage dbuf / repack
    const int t  = threadIdx.x;
    const int l  = t & 63;
    const int wv = t >> 6;
    const int lr = l & 15;
    const int lg = l >> 4;
    const int e0 = blockIdx.x * 4 * TILES;
    const int i0 = e0 >> 7;              // 4*TILES <= 16 divides 128: same i

    // ---- B fragments (M^T, bf16, L2-hot) + w fragment (col0 only) ----
    bf16x8 bfr[4][2];
#pragma unroll
    for (int n = 0; n < 4; ++n)
#pragma unroll
        for (int s = 0; s < 2; ++s)
            bfr[n][s] = *reinterpret_cast<const bf16x8*>(Mbf + (16*n + lr)*DD + s*32 + lg*8);
    const bf16x8 zerov = (bf16x8){0,0,0,0,0,0,0,0};
    bf16x8 wfrag[2];
#pragma unroll
    for (int s = 0; s < 2; ++s)
        wfrag[s] = (lr == 0) ? *reinterpret_cast<const bf16x8*>(wbf + s*32 + lg*8) : zerov;

    const int tq = (t >> 4) & 3;         // stage: e-local
    const int d0 = (t & 15) * 4;         // stage: d start
    float4 sv[8];                        // INM0 prefetch regs
    bf16x8 afr[2][2];                    // INM1 prefetch regs

    // ---- prologue: tile 0 ----
    if constexpr (INM == 0) {
        const float* ein = (const float*)einv;
#pragma unroll
        for (int it = 0; it < 8; ++it)
            sv[it] = *reinterpret_cast<const float4*>(
                         ein + ((size_t)(it*4 + wv)*EE + e0 + tq)*DD + d0);
#pragma unroll
        for (int it = 0; it < 8; ++it) {
            s16x4 o;
            o[0] = f2bf(sv[it].x); o[1] = f2bf(sv[it].y);
            o[2] = f2bf(sv[it].z); o[3] = f2bf(sv[it].w);
            *reinterpret_cast<s16x4*>(&As[0][tq][it*4 + wv][d0]) = o;
        }
    } else {
        const short* ein = (const short*)einv + (size_t)(e0 + wv)*BB*DD;
#pragma unroll
        for (int m = 0; m < 2; ++m)
#pragma unroll
            for (int s = 0; s < 2; ++s)
                afr[m][s] = *reinterpret_cast<const bf16x8*>(
                                ein + (16*m + lr)*DD + s*32 + lg*8);
    }

#pragma unroll
    for (int k = 0; k < TILES; ++k) {
        const int e  = e0 + 4*k + wv;
        const int j0 = e & 127;
        bf16x8 a[2][2];

        if constexpr (INM == 0) {
            LGKM0();                              // all waves' LDS ops drained
            __builtin_amdgcn_s_barrier();         // stage of As[k&1] visible
#pragma unroll
            for (int m = 0; m < 2; ++m)
#pragma unroll
                for (int s = 0; s < 2; ++s)
                    a[m][s] = *reinterpret_cast<const bf16x8*>(
                                  &As[k & 1][wv][16*m + lr][s*32 + lg*8]);
            if (k + 1 < TILES) {                  // issue next tile's loads NOW
                const float* ein = (const float*)einv;
#pragma unroll
                for (int it = 0; it < 8; ++it)
                    sv[it] = *reinterpret_cast<const float4*>(
                                 ein + ((size_t)(it*4 + wv)*EE + e0 + 4*(k+1) + tq)*DD + d0);
            }
        } else {
#pragma unroll
            for (int m = 0; m < 2; ++m)
#pragma unroll
                for (int s = 0; s < 2; ++s)
                    a[m][s] = afr[m][s];
            if (k + 1 < TILES) {                  // prefetch next tile's frags
                const short* ein = (const short*)einv + (size_t)(e0 + 4*(k+1) + wv)*BB*DD;
#pragma unroll
                for (int m = 0; m < 2; ++m)
#pragma unroll
                    for (int s = 0; s < 2; ++s)
                        afr[m][s] = *reinterpret_cast<const bf16x8*>(
                                        ein + (16*m + lr)*DD + s*32 + lg*8);
            }
        }

        // ---- acc init = PsT[j0] + PdT[i0] (fragment layout, L2-hot) ----
        f32x4 acc[2][4];
        f32x4 uacc[2];
        {
            const float* psb = PsT + j0*2048;
            const float* pdb = PdT + i0*2048;
#pragma unroll
            for (int m = 0; m < 2; ++m) {
                uacc[m] = (f32x4){0.f, 0.f, 0.f, 0.f};
#pragma unroll
                for (int n = 0; n < 4; ++n) {
                    const float4 aa = *reinterpret_cast<const float4*>(psb + (m*4+n)*256 + l*4);
                    const float4 cc = *reinterpret_cast<const float4*>(pdb + (m*4+n)*256 + l*4);
                    acc[m][n] = (f32x4){aa.x+cc.x, aa.y+cc.y, aa.z+cc.z, aa.w+cc.w};
                }
            }
        }

        // ---- MFMA: 16 z-tiles + 4 u-tiles ----
#pragma unroll
        for (int m = 0; m < 2; ++m) {
#pragma unroll
            for (int n = 0; n < 4; ++n)
                acc[m][n] = __builtin_amdgcn_mfma_f32_16x16x32_bf16(a[m][0], bfr[n][0], acc[m][n], 0, 0, 0);
            uacc[m] = __builtin_amdgcn_mfma_f32_16x16x32_bf16(a[m][0], wfrag[0], uacc[m], 0, 0, 0);
#pragma unroll
            for (int n = 0; n < 4; ++n)
                acc[m][n] = __builtin_amdgcn_mfma_f32_16x16x32_bf16(a[m][1], bfr[n][1], acc[m][n], 0, 0, 0);
            uacc[m] = __builtin_amdgcn_mfma_f32_16x16x32_bf16(a[m][1], wfrag[1], uacc[m], 0, 0, 0);
        }

        // ---- BN stats (channel == wave, 2048 elems) ----
        float s1 = 0.f, s2 = 0.f;
#pragma unroll
        for (int m = 0; m < 2; ++m)
#pragma unroll
            for (int n = 0; n < 4; ++n)
#pragma unroll
                for (int q = 0; q < 4; ++q) { float v = acc[m][n][q]; s1 += v; s2 += v*v; }
#pragma unroll
        for (int off = 1; off < 64; off <<= 1) {
            s1 += __shfl_xor(s1, off);
            s2 += __shfl_xor(s2, off);
        }
        const float mean = s1 * (1.f/2048.f);
        const float var  = s2 * (1.f/2048.f) - mean*mean;
        const float sc = ge[e] * rsqrtf(var + EPSI);
        const float sh = be[e] - mean*sc;

        // ---- normalize + ELU on fragments ----
#pragma unroll
        for (int m = 0; m < 2; ++m)
#pragma unroll
            for (int n = 0; n < 4; ++n)
#pragma unroll
                for (int q = 0; q < 4; ++q)
                    acc[m][n][q] = elu(acc[m][n][q]*sc + sh);

        // ---- u store ----
        if (lr == 0) {
#pragma unroll
            for (int m = 0; m < 2; ++m)
#pragma unroll
                for (int q = 0; q < 4; ++q)
                    uout[(size_t)(16*m + 4*lg + q)*EE + e] = uacc[m][q];
        }

        // ---- stage tail (INM0): convert+write NEXT tile into other buffer.
        //      The f2bf here is the vmcnt wait for sv — one full epilogue of
        //      latency has passed since issue. Different buffer than repack. ----
        if constexpr (INM == 0) {
            if (k + 1 < TILES) {
#pragma unroll
                for (int it = 0; it < 8; ++it) {
                    s16x4 o;
                    o[0] = f2bf(sv[it].x); o[1] = f2bf(sv[it].y);
                    o[2] = f2bf(sv[it].z); o[3] = f2bf(sv[it].w);
                    *reinterpret_cast<s16x4*>(&As[(k+1) & 1][tq][it*4 + wv][d0]) = o;
                }
            }
        }

        // ---- repack + store, through this wave's OWN section of As[cur] ----
        float (*Z)[68] = reinterpret_cast<float (*)[68]>(
            &As[(INM == 0) ? (k & 1) : 0][wv][0][0]);     // 4352B < 4608B section
        LGKM0();                              // own frag reads of this section done
#pragma unroll
        for (int h = 0; h < 2; ++h) {
#pragma unroll
            for (int n = 0; n < 4; ++n)
#pragma unroll
                for (int q = 0; q < 4; ++q)
                    Z[4*lg + q][16*n + lr] = acc[h][n][q];
            LGKM0();                          // RAW: repack writes visible
            if constexpr (OUTM == 0) {
                float* eout = (float*)eoutv;
#pragma unroll
                for (int it = 0; it < 4; ++it) {
                    const int rr = lg + 4*it;            // 0..15
                    const int b  = 16*h + rr;
                    float4 z = *reinterpret_cast<float4*>(&Z[rr][lr*4]);
                    *reinterpret_cast<float4*>(eout + ((size_t)b*EE + e)*DD + lr*4) = z;
                }
            } else {
                short* eout = (short*)eoutv + (size_t)e*BB*DD;   // dense block
#pragma unroll
                for (int it = 0; it < 2; ++it) {
                    const int rr = (l >> 3) + 8*it;      // 0..15
                    const int b  = 16*h + rr;
                    const int c0 = (l & 7)*8;
                    float4 zlo = *reinterpret_cast<float4*>(&Z[rr][c0]);
                    float4 zhi = *reinterpret_cast<float4*>(&Z[rr][c0+4]);
                    bf16x8 o;
                    o[0]=f2bf(zlo.x); o[1]=f2bf(zlo.y); o[2]=f2bf(zlo.z); o[3]=f2bf(zlo.w);
                    o[4]=f2bf(zhi.x); o[5]=f2bf(zhi.y); o[6]=f2bf(zhi.z); o[7]=f2bf(zhi.w);
                    *reinterpret_cast<bf16x8*>(eout + b*DD + c0) = o;
                }
            }
            LGKM0();                          // WAR: half-h reads done before h+1
        }
    }
}

// ---------------------------------------------------------------------------
// k_attn: per (b,i): logits = lrelu(s[j] + t[i] + u[b,i*N+j]) -> softmax over j
//         agg[b,i,:] = sum_j attn_j * zh[b,j,:]
__global__ void k_attn(const float* __restrict__ sI, const float* __restrict__ tI,
                       const float* __restrict__ u, const float* __restrict__ zh,
                       float* __restrict__ agg)
{
    int blk = blockIdx.x; int b = blk >> 7, i = blk & 127;
    int l = threadIdx.x;
    __shared__ float at[NN];
    float ti = tI[blk];
    float l0 = sI[b*NN + l]      + ti + u[b*EE + i*NN + l];
    float l1 = sI[b*NN + l + 64] + ti + u[b*EE + i*NN + l + 64];
    l0 = l0 >= 0.f ? l0 : 0.01f*l0;
    l1 = l1 >= 0.f ? l1 : 0.01f*l1;
    float mx = fmaxf(l0, l1);
#pragma unroll
    for (int off = 32; off; off >>= 1) mx = fmaxf(mx, __shfl_xor(mx, off));
    float e0 = __expf(l0 - mx), e1 = __expf(l1 - mx);
    float sm = e0 + e1;
#pragma unroll
    for (int off = 32; off; off >>= 1) sm += __shfl_xor(sm, off);
    float inv = 1.f / sm;
    at[l]      = e0 * inv;
    at[l + 64] = e1 * inv;
    __syncthreads();
    float acc = 0.f;
    for (int j = 0; j < NN; ++j) acc += at[j] * zh[(b*NN + j)*DD + l];
    agg[(b*NN + i)*DD + l] = acc;
}

// ---------------------------------------------------------------------------
// k_vbn: vertex BN (channel i over b,d) + residual + ELU
__global__ void k_vbn(const float* __restrict__ agg, const float* __restrict__ xres,
                      const float* __restrict__ gv, const float* __restrict__ bv,
                      float* __restrict__ xout)
{
    int i = blockIdx.x, t = threadIdx.x;
    float vals[8];
    float s1 = 0.f, s2 = 0.f;
#pragma unroll
    for (int q = 0; q < 8; ++q) {
        int m = t + 256*q; int b = m >> 6, d = m & 63;
        float v = agg[(b*NN + i)*DD + d];
        vals[q] = v; s1 += v; s2 += v*v;
    }
#pragma unroll
    for (int off = 1; off < 64; off <<= 1) {
        s1 += __shfl_xor(s1, off);
        s2 += __shfl_xor(s2, off);
    }
    __shared__ float r1[4], r2[4];
    int wv = t >> 6;
    if ((t & 63) == 0) { r1[wv] = s1; r2[wv] = s2; }
    __syncthreads();
    s1 = r1[0] + r1[1] + r1[2] + r1[3];
    s2 = r2[0] + r2[1] + r2[2] + r2[3];
    float mean  = s1 * (1.f/2048.f);
    float var   = s2 * (1.f/2048.f) - mean*mean;
    float scale = gv[i] * rsqrtf(var + EPSI);
    float shift = bv[i] - mean*scale;
#pragma unroll
    for (int q = 0; q < 8; ++q) {
        int m = t + 256*q; int b = m >> 6, d = m & 63;
        float v = vals[q]*scale + shift + xres[(b*NN + i)*DD + d];
        xout[(b*NN + i)*DD + d] = v > 0.f ? v : __expf(v) - 1.f;
    }
}

// ---------------------------------------------------------------------------
extern "C" void kernel_launch(void* const* d_in, const int* in_sizes, int n_in,
                              void* d_out, int out_size, void* d_ws, size_t ws_size,
                              hipStream_t stream)
{
    const float* x    = (const float*)d_in[0];
    const float* edge = (const float*)d_in[1];
    const float* Wh1  = (const float*)d_in[2];
    const float* We1  = (const float*)d_in[3];
    const float* Wp1  = (const float*)d_in[4];
    const float* Wa1  = (const float*)d_in[5];
    const float* Wh2  = (const float*)d_in[6];
    const float* We2  = (const float*)d_in[7];
    const float* Wp2  = (const float*)d_in[8];
    const float* Wa2  = (const float*)d_in[9];
    const float* gv1  = (const float*)d_in[10];
    const float* bv1  = (const float*)d_in[11];
    const float* ge1  = (const float*)d_in[12];
    const float* be1  = (const float*)d_in[13];
    const float* gv2  = (const float*)d_in[14];
    const float* bv2  = (const float*)d_in[15];
    const float* ge2  = (const float*)d_in[16];
    const float* be2  = (const float*)d_in[17];

    float* xout = (float*)d_out;                    // (B,N,D)
    float* eout = (float*)d_out + BB*NN*DD;         // (B,E,D) final edge output

    float* ws  = (float*)d_ws;
    short* Mbf = (short*)ws;  ws += DD*DD/2;        // bf16 M^T (8 KB)
    short* wbf = (short*)ws;  ws += DD/2;           // bf16 w
    float* zh  = ws;  ws += BB*NN*DD;
    float* PsT = ws;  ws += NN*BB*DD;               // fragment-layout Ps (1 MB)
    float* PdT = ws;  ws += NN*BB*DD;               // fragment-layout Pd (1 MB)
    float* sb  = ws;  ws += BB*NN;
    float* tb  = ws;  ws += BB*NN;
    float* ub  = ws;  ws += BB*EE;
    float* agg = ws;  ws += BB*NN*DD;
    float* x1  = ws;  ws += BB*NN*DD;
    short* ebf = (short*)ws;                        // (E,B,D) bf16 intermediate (67 MB)
    const size_t need = ((size_t)(ws - (float*)d_ws))*4 + (size_t)EE*BB*DD*2;

    const bool dense = (ws_size >= need);

    // ----- layer 1 -----
    k_node<<<BB*NN + 64, 64, 0, stream>>>(x, Wh1, Wp1, We1, Wa1, zh, PsT, PdT, sb, tb, Mbf, wbf);
    if (dense)
        k_edge<0,1,4><<<EE/16, 256, 0, stream>>>(edge, Mbf, wbf, PsT, PdT, ge1, be1, ebf, ub);
    else
        k_edge<0,0,1><<<EE/4, 256, 0, stream>>>(edge, Mbf, wbf, PsT, PdT, ge1, be1, eout, ub);
    k_attn<<<BB*NN, 64, 0, stream>>>(sb, tb, ub, zh, agg);
    k_vbn<<<NN, 256, 0, stream>>>(agg, x, gv1, bv1, x1);
    // ----- layer 2 -----
    k_node<<<BB*NN + 64, 64, 0, stream>>>(x1, Wh2, Wp2, We2, Wa2, zh, PsT, PdT, sb, tb, Mbf, wbf);
    if (dense)
        k_edge<1,0,4><<<EE/16, 256, 0, stream>>>(ebf, Mbf, wbf, PsT, PdT, ge2, be2, eout, ub);
    else  // in-place on eout: staged reads complete at the barrier before stores
        k_edge<0,0,1><<<EE/4, 256, 0, stream>>>(eout, Mbf, wbf, PsT, PdT, ge2, be2, eout, ub);
    k_attn<<<BB*NN, 64, 0, stream>>>(sb, tb, ub, zh, agg);
    k_vbn<<<NN, 256, 0, stream>>>(agg, x1, gv2, bv2, xout);
}

// Round 14
// 192.532 us; speedup vs baseline: 1.3440x; 1.3440x over previous
//
#include <hip/hip_runtime.h>
#include <math.h>

#define BB 32
#define NN 128
#define DD 64
#define EE (NN*NN)          // 16384
#define EPSI 1e-5f

typedef __attribute__((ext_vector_type(8))) short bf16x8;   // 8 bf16 (4 VGPRs)
typedef __attribute__((ext_vector_type(4))) short s16x4;    // 4 bf16 (2 VGPRs)
typedef __attribute__((ext_vector_type(4))) float f32x4;

// lgkmcnt(0)-only wait (NOT s_waitcnt 0: that drains vmcnt too -> store stalls)
#define LGKM0() do { asm volatile("s_waitcnt lgkmcnt(0)" ::: "memory"); \
                     __builtin_amdgcn_sched_barrier(0); } while (0)

__device__ __forceinline__ short f2bf(float f) {
    union { float f; unsigned u; } v; v.f = f;
    unsigned u = v.u;
    unsigned r = (u + 0x7FFFu + ((u >> 16) & 1u)) >> 16;    // RNE
    return (short)r;
}
__device__ __forceinline__ float elu(float v) {
    return v > 0.f ? v : __expf(v) - 1.f;     // v_exp_f32 path
}

// ---------------------------------------------------------------------------
// k_node (+ folded fold): blocks [0, B*N): per (b,n) row:
//   z_h = x @ Wh^T ; PsT/PdT in MFMA C-fragment layout ; s,t scalars.
// blocks [B*N, B*N+64): fold — Mbf[d][k] = bf16(sum_o Wp[d][128+o]*We[o][k]),
//   block ff==0 also wbf[k] = bf16(sum_o Wa[128+o]*We[o][k]).
__global__ void k_node(const float* __restrict__ x, const float* __restrict__ Wh,
                       const float* __restrict__ Wp, const float* __restrict__ We,
                       const float* __restrict__ Wa,
                       float* __restrict__ zh, float* __restrict__ PsT,
                       float* __restrict__ PdT, float* __restrict__ sO,
                       float* __restrict__ tO,
                       short* __restrict__ Mbf, short* __restrict__ wbf)
{
    const int row = blockIdx.x;
    const int d = threadIdx.x;           // 0..63
    if (row >= BB*NN) {                  // ---- fold tail blocks ----
        const int ff = row - BB*NN;      // 0..63 == output row d'
        float acc = 0.f;
        for (int o = 0; o < DD; ++o)
            acc += Wp[ff*192 + 128 + o] * We[o*DD + d];
        Mbf[ff*DD + d] = f2bf(acc);
        if (ff == 0) {
            float aw = 0.f;
            for (int o = 0; o < DD; ++o)
                aw += Wa[128 + o] * We[o*DD + d];
            wbf[d] = f2bf(aw);
        }
        return;
    }
    const int b = row >> 7, n = row & 127;
    __shared__ float xr[DD];
    __shared__ float zr[DD];
    xr[d] = x[row*DD + d];
    __syncthreads();
    float acc = 0.f;
#pragma unroll
    for (int k = 0; k < DD; ++k) acc += xr[k] * Wh[d*DD + k];
    zr[d] = acc;
    zh[row*DD + d] = acc;
    __syncthreads();
    float a0 = 0.f, a1 = 0.f;
#pragma unroll
    for (int o = 0; o < DD; ++o) {
        float z = zr[o];
        a0 += Wp[d*192 + o]      * z;
        a1 += Wp[d*192 + 64 + o] * z;
    }
    const int fi = ((b >> 4)*4 + (d >> 4))*256 + (((b >> 2) & 3)*16 + (d & 15))*4 + (b & 3);
    PsT[n*2048 + fi] = a0;
    PdT[n*2048 + fi] = a1;
    float sv = zr[d] * Wa[d];
    float tv = zr[d] * Wa[64 + d];
#pragma unroll
    for (int off = 32; off; off >>= 1) {
        sv += __shfl_xor(sv, off);
        tv += __shfl_xor(tv, off);
    }
    if (d == 0) { sO[row] = sv; tO[row] = tv; }
}

// ---------------------------------------------------------------------------
// k_edge (v8 body, launch_bounds(256,4) — best measured: 83+83 µs):
//   z = edge @ M^T + Ps[b,j] + Pd[b,i] -> BN(per-e over b,d) -> ELU
//   u[b,e] = edge . w  via a 5th MFMA B-tile (col0 = w)
// 256 threads = 4 waves; wave wv owns channel e = 4*blk + wv (32 b x 64 d).
// INM==0: A fp32 (B,E,D); rows (b, e0..e0+3) are contiguous 1KB runs ->
//   cooperative coalesced stage into bf16 LDS As[el][32][72] (conflict-free
//   for staged writes and fragment ds_read_b128).
// INM==1: A bf16 (E,B,D) dense -> direct coalesced fragment loads.
// Epilogue: BN stats + normalize + ELU on fragments (full-wave shfl), then
// repack through the (reused) per-wave LDS section with lgkmcnt-only waits.
// OUTM: 0 = fp32 (B,E,D) (d_out); 1 = bf16 (E,B,D) dense intermediate.
template <int INM, int OUTM>
__global__ __launch_bounds__(256, 4) void k_edge(
    const void* einv,
    const short* __restrict__ Mbf,   // (D,D) bf16
    const short* __restrict__ wbf,   // (D)   bf16
    const float* __restrict__ PsT,   // (N, 2048) fragment layout
    const float* __restrict__ PdT,   // (N, 2048) fragment layout
    const float* __restrict__ ge, const float* __restrict__ be,
    void* eoutv, float* __restrict__ uout)
{
    __shared__ short As[4][32][72];  // 18,432 B; staged A; reused as repack buf
    const int t  = threadIdx.x;
    const int l  = t & 63;
    const int wv = t >> 6;
    const int lr = l & 15;
    const int lg = l >> 4;
    const int e0 = blockIdx.x * 4;
    const int e  = e0 + wv;
    const int i0 = e >> 7, j0 = e & 127;

    // ---- A fragments ----
    bf16x8 afr[2][2];                 // [m][k-half]
    if constexpr (INM == 0) {
        const float* ein = (const float*)einv;
        const int tq = (t >> 4) & 3;          // e-local
        const int d0 = (t & 15) * 4;
        float4 sv[8];
#pragma unroll
        for (int it = 0; it < 8; ++it) {
            const int b = it*4 + wv;
            sv[it] = *reinterpret_cast<const float4*>(
                         ein + ((size_t)b*EE + e0 + tq)*DD + d0);
        }
#pragma unroll
        for (int it = 0; it < 8; ++it) {
            const int b = it*4 + wv;
            s16x4 o;
            o[0] = f2bf(sv[it].x); o[1] = f2bf(sv[it].y);
            o[2] = f2bf(sv[it].z); o[3] = f2bf(sv[it].w);
            *reinterpret_cast<s16x4*>(&As[tq][b][d0]) = o;
        }
        __syncthreads();
#pragma unroll
        for (int m = 0; m < 2; ++m)
#pragma unroll
            for (int s = 0; s < 2; ++s)
                afr[m][s] = *reinterpret_cast<const bf16x8*>(
                                &As[wv][16*m + lr][s*32 + lg*8]);
    } else {
        const short* ein = (const short*)einv + (size_t)e*BB*DD;   // dense block
#pragma unroll
        for (int m = 0; m < 2; ++m)
#pragma unroll
            for (int s = 0; s < 2; ++s)
                afr[m][s] = *reinterpret_cast<const bf16x8*>(
                                ein + (16*m + lr)*DD + s*32 + lg*8);
    }

    // ---- B fragments (M^T, bf16, L2-hot) + w fragment (col0 only) ----
    bf16x8 bfr[4][2];
#pragma unroll
    for (int n = 0; n < 4; ++n)
#pragma unroll
        for (int s = 0; s < 2; ++s)
            bfr[n][s] = *reinterpret_cast<const bf16x8*>(Mbf + (16*n + lr)*DD + s*32 + lg*8);
    const bf16x8 zerov = (bf16x8){0,0,0,0,0,0,0,0};
    bf16x8 wfrag[2];
#pragma unroll
    for (int s = 0; s < 2; ++s)
        wfrag[s] = (lr == 0) ? *reinterpret_cast<const bf16x8*>(wbf + s*32 + lg*8) : zerov;

    // ---- acc init = PsT[j0] + PdT[i0]: dense fragment-layout loads ----
    f32x4 acc[2][4];
    f32x4 uacc[2];
    {
        const float* psb = PsT + j0*2048;
        const float* pdb = PdT + i0*2048;
#pragma unroll
        for (int m = 0; m < 2; ++m) {
            uacc[m] = (f32x4){0.f, 0.f, 0.f, 0.f};
#pragma unroll
            for (int n = 0; n < 4; ++n) {
                const float4 a = *reinterpret_cast<const float4*>(psb + (m*4+n)*256 + l*4);
                const float4 c = *reinterpret_cast<const float4*>(pdb + (m*4+n)*256 + l*4);
                acc[m][n] = (f32x4){a.x+c.x, a.y+c.y, a.z+c.z, a.w+c.w};
            }
        }
    }

    // ---- MFMA: 16 z-tiles + 4 u-tiles ----
#pragma unroll
    for (int m = 0; m < 2; ++m) {
#pragma unroll
        for (int n = 0; n < 4; ++n)
            acc[m][n] = __builtin_amdgcn_mfma_f32_16x16x32_bf16(afr[m][0], bfr[n][0], acc[m][n], 0, 0, 0);
        uacc[m] = __builtin_amdgcn_mfma_f32_16x16x32_bf16(afr[m][0], wfrag[0], uacc[m], 0, 0, 0);
#pragma unroll
        for (int n = 0; n < 4; ++n)
            acc[m][n] = __builtin_amdgcn_mfma_f32_16x16x32_bf16(afr[m][1], bfr[n][1], acc[m][n], 0, 0, 0);
        uacc[m] = __builtin_amdgcn_mfma_f32_16x16x32_bf16(afr[m][1], wfrag[1], uacc[m], 0, 0, 0);
    }

    // ---- BN stats on fragments (channel == wave, 2048 elems) ----
    float s1 = 0.f, s2 = 0.f;
#pragma unroll
    for (int m = 0; m < 2; ++m)
#pragma unroll
        for (int n = 0; n < 4; ++n)
#pragma unroll
            for (int q = 0; q < 4; ++q) { float v = acc[m][n][q]; s1 += v; s2 += v*v; }
#pragma unroll
    for (int off = 1; off < 64; off <<= 1) {
        s1 += __shfl_xor(s1, off);
        s2 += __shfl_xor(s2, off);
    }
    const float mean = s1 * (1.f/2048.f);
    const float var  = s2 * (1.f/2048.f) - mean*mean;
    const float sc = ge[e] * rsqrtf(var + EPSI);
    const float sh = be[e] - mean*sc;

    // ---- normalize + ELU on fragments ----
#pragma unroll
    for (int m = 0; m < 2; ++m)
#pragma unroll
        for (int n = 0; n < 4; ++n)
#pragma unroll
            for (int q = 0; q < 4; ++q)
                acc[m][n][q] = elu(acc[m][n][q]*sc + sh);

    // ---- u store (col0 lanes hold u[b] for b = 16m+4lg+q) ----
    if (lr == 0) {
#pragma unroll
        for (int m = 0; m < 2; ++m)
#pragma unroll
            for (int q = 0; q < 4; ++q)
                uout[(size_t)(16*m + 4*lg + q)*EE + e] = uacc[m][q];
    }

    // ---- repack + store, 16-row halves through this wave's own LDS section ----
    float (*Z)[68] = reinterpret_cast<float (*)[68]>(&As[wv][0][0]);  // 4352B < 4608B section
    LGKM0();                              // fragment reads of As[wv] fully drained
#pragma unroll
    for (int h = 0; h < 2; ++h) {
#pragma unroll
        for (int n = 0; n < 4; ++n)
#pragma unroll
            for (int q = 0; q < 4; ++q)
                Z[4*lg + q][16*n + lr] = acc[h][n][q];
        LGKM0();                          // RAW: repack writes visible to reads
        if constexpr (OUTM == 0) {
            float* eout = (float*)eoutv;
#pragma unroll
            for (int it = 0; it < 4; ++it) {
                const int rr = lg + 4*it;            // 0..15
                const int b  = 16*h + rr;
                float4 z = *reinterpret_cast<float4*>(&Z[rr][lr*4]);
                *reinterpret_cast<float4*>(eout + ((size_t)b*EE + e)*DD + lr*4) = z;
            }
        } else {
            short* eout = (short*)eoutv + (size_t)e*BB*DD;   // dense channel block
#pragma unroll
            for (int it = 0; it < 2; ++it) {
                const int rr = (l >> 3) + 8*it;      // 0..15
                const int b  = 16*h + rr;
                const int c0 = (l & 7)*8;
                float4 zlo = *reinterpret_cast<float4*>(&Z[rr][c0]);
                float4 zhi = *reinterpret_cast<float4*>(&Z[rr][c0+4]);
                bf16x8 o;
                o[0]=f2bf(zlo.x); o[1]=f2bf(zlo.y); o[2]=f2bf(zlo.z); o[3]=f2bf(zlo.w);
                o[4]=f2bf(zhi.x); o[5]=f2bf(zhi.y); o[6]=f2bf(zhi.z); o[7]=f2bf(zhi.w);
                *reinterpret_cast<bf16x8*>(eout + b*DD + c0) = o;
            }
        }
        LGKM0();                          // WAR: half-h reads done before h+1 overwrite
    }
}

// ---------------------------------------------------------------------------
// k_attn v2: per (b,i): logits = lrelu(s[j]+t[i]+u[b,i*N+j]) -> softmax over j
//   agg[b,i,:] = sum_j attn_j * zh[b,j,:]
// j-loop split into 4 independent accumulator chains (+unroll 4 => 16 loads
// in flight) to break the 128-deep dependent load+FMA chain.
__global__ void k_attn(const float* __restrict__ sI, const float* __restrict__ tI,
                       const float* __restrict__ u, const float* __restrict__ zh,
                       float* __restrict__ agg)
{
    int blk = blockIdx.x; int b = blk >> 7, i = blk & 127;
    int l = threadIdx.x;
    __shared__ float at[NN];
    float ti = tI[blk];
    float l0 = sI[b*NN + l]      + ti + u[b*EE + i*NN + l];
    float l1 = sI[b*NN + l + 64] + ti + u[b*EE + i*NN + l + 64];
    l0 = l0 >= 0.f ? l0 : 0.01f*l0;
    l1 = l1 >= 0.f ? l1 : 0.01f*l1;
    float mx = fmaxf(l0, l1);
#pragma unroll
    for (int off = 32; off; off >>= 1) mx = fmaxf(mx, __shfl_xor(mx, off));
    float e0 = __expf(l0 - mx), e1 = __expf(l1 - mx);
    float sm = e0 + e1;
#pragma unroll
    for (int off = 32; off; off >>= 1) sm += __shfl_xor(sm, off);
    float inv = 1.f / sm;
    at[l]      = e0 * inv;
    at[l + 64] = e1 * inv;
    __syncthreads();
    const float* zb = zh + (size_t)b*NN*DD + l;
    float a0 = 0.f, a1 = 0.f, a2 = 0.f, a3 = 0.f;
#pragma unroll 4
    for (int j = 0; j < NN; j += 4) {
        a0 += at[j]     * zb[(j)    *DD];
        a1 += at[j + 1] * zb[(j + 1)*DD];
        a2 += at[j + 2] * zb[(j + 2)*DD];
        a3 += at[j + 3] * zb[(j + 3)*DD];
    }
    agg[(b*NN + i)*DD + l] = (a0 + a1) + (a2 + a3);
}

// ---------------------------------------------------------------------------
// k_vbn: vertex BN (channel i over b,d) + residual + ELU
__global__ void k_vbn(const float* __restrict__ agg, const float* __restrict__ xres,
                      const float* __restrict__ gv, const float* __restrict__ bv,
                      float* __restrict__ xout)
{
    int i = blockIdx.x, t = threadIdx.x;
    float vals[8];
    float s1 = 0.f, s2 = 0.f;
#pragma unroll
    for (int q = 0; q < 8; ++q) {
        int m = t + 256*q; int b = m >> 6, d = m & 63;
        float v = agg[(b*NN + i)*DD + d];
        vals[q] = v; s1 += v; s2 += v*v;
    }
#pragma unroll
    for (int off = 1; off < 64; off <<= 1) {
        s1 += __shfl_xor(s1, off);
        s2 += __shfl_xor(s2, off);
    }
    __shared__ float r1[4], r2[4];
    int wv = t >> 6;
    if ((t & 63) == 0) { r1[wv] = s1; r2[wv] = s2; }
    __syncthreads();
    s1 = r1[0] + r1[1] + r1[2] + r1[3];
    s2 = r2[0] + r2[1] + r2[2] + r2[3];
    float mean  = s1 * (1.f/2048.f);
    float var   = s2 * (1.f/2048.f) - mean*mean;
    float scale = gv[i] * rsqrtf(var + EPSI);
    float shift = bv[i] - mean*scale;
#pragma unroll
    for (int q = 0; q < 8; ++q) {
        int m = t + 256*q; int b = m >> 6, d = m & 63;
        float v = vals[q]*scale + shift + xres[(b*NN + i)*DD + d];
        xout[(b*NN + i)*DD + d] = v > 0.f ? v : __expf(v) - 1.f;
    }
}

// ---------------------------------------------------------------------------
extern "C" void kernel_launch(void* const* d_in, const int* in_sizes, int n_in,
                              void* d_out, int out_size, void* d_ws, size_t ws_size,
                              hipStream_t stream)
{
    const float* x    = (const float*)d_in[0];
    const float* edge = (const float*)d_in[1];
    const float* Wh1  = (const float*)d_in[2];
    const float* We1  = (const float*)d_in[3];
    const float* Wp1  = (const float*)d_in[4];
    const float* Wa1  = (const float*)d_in[5];
    const float* Wh2  = (const float*)d_in[6];
    const float* We2  = (const float*)d_in[7];
    const float* Wp2  = (const float*)d_in[8];
    const float* Wa2  = (const float*)d_in[9];
    const float* gv1  = (const float*)d_in[10];
    const float* bv1  = (const float*)d_in[11];
    const float* ge1  = (const float*)d_in[12];
    const float* be1  = (const float*)d_in[13];
    const float* gv2  = (const float*)d_in[14];
    const float* bv2  = (const float*)d_in[15];
    const float* ge2  = (const float*)d_in[16];
    const float* be2  = (const float*)d_in[17];

    float* xout = (float*)d_out;                    // (B,N,D)
    float* eout = (float*)d_out + BB*NN*DD;         // (B,E,D) final edge output

    float* ws  = (float*)d_ws;
    short* Mbf = (short*)ws;  ws += DD*DD/2;        // bf16 M^T (8 KB)
    short* wbf = (short*)ws;  ws += DD/2;           // bf16 w
    float* zh  = ws;  ws += BB*NN*DD;
    float* PsT = ws;  ws += NN*BB*DD;               // fragment-layout Ps (1 MB)
    float* PdT = ws;  ws += NN*BB*DD;               // fragment-layout Pd (1 MB)
    float* sb  = ws;  ws += BB*NN;
    float* tb  = ws;  ws += BB*NN;
    float* ub  = ws;  ws += BB*EE;
    float* agg = ws;  ws += BB*NN*DD;
    float* x1  = ws;  ws += BB*NN*DD;
    short* ebf = (short*)ws;                        // (E,B,D) bf16 intermediate (67 MB)
    const size_t need = ((size_t)(ws - (float*)d_ws))*4 + (size_t)EE*BB*DD*2;

    const bool dense = (ws_size >= need);

    // ----- layer 1 -----
    k_node<<<BB*NN + 64, 64, 0, stream>>>(x, Wh1, Wp1, We1, Wa1, zh, PsT, PdT, sb, tb, Mbf, wbf);
    if (dense)
        k_edge<0,1><<<EE/4, 256, 0, stream>>>(edge, Mbf, wbf, PsT, PdT, ge1, be1, ebf, ub);
    else
        k_edge<0,0><<<EE/4, 256, 0, stream>>>(edge, Mbf, wbf, PsT, PdT, ge1, be1, eout, ub);
    k_attn<<<BB*NN, 64, 0, stream>>>(sb, tb, ub, zh, agg);
    k_vbn<<<NN, 256, 0, stream>>>(agg, x, gv1, bv1, x1);
    // ----- layer 2 -----
    k_node<<<BB*NN + 64, 64, 0, stream>>>(x1, Wh2, Wp2, We2, Wa2, zh, PsT, PdT, sb, tb, Mbf, wbf);
    if (dense)
        k_edge<1,0><<<EE/4, 256, 0, stream>>>(ebf, Mbf, wbf, PsT, PdT, ge2, be2, eout, ub);
    else  // in-place on eout: staged reads complete at __syncthreads before stores
        k_edge<0,0><<<EE/4, 256, 0, stream>>>(eout, Mbf, wbf, PsT, PdT, ge2, be2, eout, ub);
    k_attn<<<BB*NN, 64, 0, stream>>>(sb, tb, ub, zh, agg);
    k_vbn<<<NN, 256, 0, stream>>>(agg, x1, gv2, bv2, xout);
}

// Round 15
// 182.657 us; speedup vs baseline: 1.4166x; 1.0541x over previous
//
#include <hip/hip_runtime.h>
#include <math.h>

#define BB 32
#define NN 128
#define DD 64
#define EE (NN*NN)          // 16384
#define EPSI 1e-5f

typedef __attribute__((ext_vector_type(8))) short bf16x8;   // 8 bf16 (4 VGPRs)
typedef __attribute__((ext_vector_type(4))) short s16x4;    // 4 bf16 (2 VGPRs)
typedef __attribute__((ext_vector_type(4))) float f32x4;

// lgkmcnt(0)-only wait (NOT s_waitcnt 0: that drains vmcnt too -> store stalls)
#define LGKM0() do { asm volatile("s_waitcnt lgkmcnt(0)" ::: "memory"); \
                     __builtin_amdgcn_sched_barrier(0); } while (0)

__device__ __forceinline__ short f2bf(float f) {
    union { float f; unsigned u; } v; v.f = f;
    unsigned u = v.u;
    unsigned r = (u + 0x7FFFu + ((u >> 16) & 1u)) >> 16;    // RNE
    return (short)r;
}
__device__ __forceinline__ float elu(float v) {
    return v > 0.f ? v : __expf(v) - 1.f;     // v_exp_f32 path
}

// ---------------------------------------------------------------------------
// k_node (+ folded fold): blocks [0, B*N): per (b,n) row:
//   z_h = x @ Wh^T ; PsT/PdT in MFMA C-fragment layout ; s,t scalars.
// blocks [B*N, B*N+64): fold — M = Wp_e @ We stored FRAGMENT-MAJOR:
//   MbT[((n*2+s)*64 + lane)*8 + j] = M[d=16n+(lane&15)][k=s*32+(lane>>4)*8+j]
//   so k_edge's B-loads are lane-dense (1 segment per instruction).
//   wfT likewise (col0 = w, other lanes pre-zeroed -> no branch in k_edge).
__global__ void k_node(const float* __restrict__ x, const float* __restrict__ Wh,
                       const float* __restrict__ Wp, const float* __restrict__ We,
                       const float* __restrict__ Wa,
                       float* __restrict__ zh, float* __restrict__ PsT,
                       float* __restrict__ PdT, float* __restrict__ sO,
                       float* __restrict__ tO,
                       short* __restrict__ MbT, short* __restrict__ wfT)
{
    const int row = blockIdx.x;
    const int d = threadIdx.x;           // 0..63
    if (row >= BB*NN) {                  // ---- fold tail blocks ----
        const int ff = row - BB*NN;      // 0..63 == M row d'
        float acc = 0.f;
        for (int o = 0; o < DD; ++o)
            acc += Wp[ff*192 + 128 + o] * We[o*DD + d];
        // fragment-major scatter: n=ff>>4, lr=ff&15, s=d>>5, lg=(d>>3)&3, j=d&7
        MbT[(((ff >> 4)*2 + (d >> 5))*64 + (ff & 15) + ((d >> 3) & 3)*16)*8 + (d & 7)]
            = f2bf(acc);
        if (ff == 0) {
            for (int q = 0; q < 16; ++q) wfT[d*16 + q] = 0;   // zero 1024 shorts
            __syncthreads();
            float aw = 0.f;
            for (int o = 0; o < DD; ++o)
                aw += Wa[128 + o] * We[o*DD + d];
            // lane = lg*16 (lr==0 slot)
            wfT[((d >> 5)*64 + ((d >> 3) & 3)*16)*8 + (d & 7)] = f2bf(aw);
        }
        return;
    }
    const int b = row >> 7, n = row & 127;
    __shared__ float xr[DD];
    __shared__ float zr[DD];
    xr[d] = x[row*DD + d];
    __syncthreads();
    float acc = 0.f;
#pragma unroll
    for (int k = 0; k < DD; ++k) acc += xr[k] * Wh[d*DD + k];
    zr[d] = acc;
    zh[row*DD + d] = acc;
    __syncthreads();
    float a0 = 0.f, a1 = 0.f;
#pragma unroll
    for (int o = 0; o < DD; ++o) {
        float z = zr[o];
        a0 += Wp[d*192 + o]      * z;
        a1 += Wp[d*192 + 64 + o] * z;
    }
    const int fi = ((b >> 4)*4 + (d >> 4))*256 + (((b >> 2) & 3)*16 + (d & 15))*4 + (b & 3);
    PsT[n*2048 + fi] = a0;
    PdT[n*2048 + fi] = a1;
    float sv = zr[d] * Wa[d];
    float tv = zr[d] * Wa[64 + d];
#pragma unroll
    for (int off = 32; off; off >>= 1) {
        sv += __shfl_xor(sv, off);
        tv += __shfl_xor(tv, off);
    }
    if (d == 0) { sO[row] = sv; tO[row] = tv; }
}

// ---------------------------------------------------------------------------
// k_edge (v8 body + lane-dense fragment I/O):
//   z = edge @ M^T + Ps[b,j] + Pd[b,i] -> BN(per-e over b,d) -> ELU
//   u[b,e] = edge . w  via a 5th MFMA B-tile (col0 = w)
// 256 threads = 4 waves; wave wv owns channel e = 4*blk + wv (32 b x 64 d).
// INM==0: A fp32 (B,E,D); contiguous 1KB runs staged into bf16 LDS As.
// INM==1: A in A-FRAGMENT-MAJOR bf16 (E, 8frag, 64lane, 8) -> 4 dense loads.
// B/w: fragment-major MbT/wfT -> 10 dense loads (was ~130 gather segments).
// OUTM==0: fp32 (B,E,D) (d_out), float4 rows via LDS repack.
// OUTM==1: A-fragment-major bf16 intermediate (for the next layer's INM==1).
template <int INM, int OUTM>
__global__ __launch_bounds__(256, 4) void k_edge(
    const void* einv,
    const short* __restrict__ MbT,   // (8,64,8) bf16 fragment-major
    const short* __restrict__ wfT,   // (2,64,8) bf16 fragment-major
    const float* __restrict__ PsT,   // (N, 2048) fragment layout
    const float* __restrict__ PdT,   // (N, 2048) fragment layout
    const float* __restrict__ ge, const float* __restrict__ be,
    void* eoutv, float* __restrict__ uout)
{
    __shared__ short As[4][32][72];  // 18,432 B; staged A; reused as repack buf
    const int t  = threadIdx.x;
    const int l  = t & 63;
    const int wv = t >> 6;
    const int lr = l & 15;
    const int lg = l >> 4;
    const int e0 = blockIdx.x * 4;
    const int e  = e0 + wv;
    const int i0 = e >> 7, j0 = e & 127;

    // ---- A fragments ----
    bf16x8 afr[2][2];                 // [m][k-half]
    if constexpr (INM == 0) {
        const float* ein = (const float*)einv;
        const int tq = (t >> 4) & 3;          // e-local
        const int d0 = (t & 15) * 4;
        float4 sv[8];
#pragma unroll
        for (int it = 0; it < 8; ++it) {
            const int b = it*4 + wv;
            sv[it] = *reinterpret_cast<const float4*>(
                         ein + ((size_t)b*EE + e0 + tq)*DD + d0);
        }
#pragma unroll
        for (int it = 0; it < 8; ++it) {
            const int b = it*4 + wv;
            s16x4 o;
            o[0] = f2bf(sv[it].x); o[1] = f2bf(sv[it].y);
            o[2] = f2bf(sv[it].z); o[3] = f2bf(sv[it].w);
            *reinterpret_cast<s16x4*>(&As[tq][b][d0]) = o;
        }
        __syncthreads();
#pragma unroll
        for (int m = 0; m < 2; ++m)
#pragma unroll
            for (int s = 0; s < 2; ++s)
                afr[m][s] = *reinterpret_cast<const bf16x8*>(
                                &As[wv][16*m + lr][s*32 + lg*8]);
    } else {
        const short* ein = (const short*)einv + (size_t)e*BB*DD;  // frag-major blk
#pragma unroll
        for (int m = 0; m < 2; ++m)
#pragma unroll
            for (int s = 0; s < 2; ++s)
                afr[m][s] = *reinterpret_cast<const bf16x8*>(
                                ein + ((m*2 + s)*64 + l)*8);      // lane-dense 1KB
    }

    // ---- B fragments + w fragment: lane-dense fragment-major loads ----
    bf16x8 bfr[4][2];
#pragma unroll
    for (int n = 0; n < 4; ++n)
#pragma unroll
        for (int s = 0; s < 2; ++s)
            bfr[n][s] = *reinterpret_cast<const bf16x8*>(MbT + ((n*2 + s)*64 + l)*8);
    bf16x8 wfrag[2];
#pragma unroll
    for (int s = 0; s < 2; ++s)
        wfrag[s] = *reinterpret_cast<const bf16x8*>(wfT + (s*64 + l)*8);

    // ---- acc init = PsT[j0] + PdT[i0]: dense fragment-layout loads ----
    f32x4 acc[2][4];
    f32x4 uacc[2];
    {
        const float* psb = PsT + j0*2048;
        const float* pdb = PdT + i0*2048;
#pragma unroll
        for (int m = 0; m < 2; ++m) {
            uacc[m] = (f32x4){0.f, 0.f, 0.f, 0.f};
#pragma unroll
            for (int n = 0; n < 4; ++n) {
                const float4 a = *reinterpret_cast<const float4*>(psb + (m*4+n)*256 + l*4);
                const float4 c = *reinterpret_cast<const float4*>(pdb + (m*4+n)*256 + l*4);
                acc[m][n] = (f32x4){a.x+c.x, a.y+c.y, a.z+c.z, a.w+c.w};
            }
        }
    }

    // ---- MFMA: 16 z-tiles + 4 u-tiles ----
#pragma unroll
    for (int m = 0; m < 2; ++m) {
#pragma unroll
        for (int n = 0; n < 4; ++n)
            acc[m][n] = __builtin_amdgcn_mfma_f32_16x16x32_bf16(afr[m][0], bfr[n][0], acc[m][n], 0, 0, 0);
        uacc[m] = __builtin_amdgcn_mfma_f32_16x16x32_bf16(afr[m][0], wfrag[0], uacc[m], 0, 0, 0);
#pragma unroll
        for (int n = 0; n < 4; ++n)
            acc[m][n] = __builtin_amdgcn_mfma_f32_16x16x32_bf16(afr[m][1], bfr[n][1], acc[m][n], 0, 0, 0);
        uacc[m] = __builtin_amdgcn_mfma_f32_16x16x32_bf16(afr[m][1], wfrag[1], uacc[m], 0, 0, 0);
    }

    // ---- BN stats on fragments (channel == wave, 2048 elems) ----
    float s1 = 0.f, s2 = 0.f;
#pragma unroll
    for (int m = 0; m < 2; ++m)
#pragma unroll
        for (int n = 0; n < 4; ++n)
#pragma unroll
            for (int q = 0; q < 4; ++q) { float v = acc[m][n][q]; s1 += v; s2 += v*v; }
#pragma unroll
    for (int off = 1; off < 64; off <<= 1) {
        s1 += __shfl_xor(s1, off);
        s2 += __shfl_xor(s2, off);
    }
    const float mean = s1 * (1.f/2048.f);
    const float var  = s2 * (1.f/2048.f) - mean*mean;
    const float sc = ge[e] * rsqrtf(var + EPSI);
    const float sh = be[e] - mean*sc;

    // ---- normalize + ELU on fragments ----
#pragma unroll
    for (int m = 0; m < 2; ++m)
#pragma unroll
        for (int n = 0; n < 4; ++n)
#pragma unroll
            for (int q = 0; q < 4; ++q)
                acc[m][n][q] = elu(acc[m][n][q]*sc + sh);

    // ---- u store (col0 lanes hold u[b] for b = 16m+4lg+q) ----
    if (lr == 0) {
#pragma unroll
        for (int m = 0; m < 2; ++m)
#pragma unroll
            for (int q = 0; q < 4; ++q)
                uout[(size_t)(16*m + 4*lg + q)*EE + e] = uacc[m][q];
    }

    // ---- repack + store, 16-row halves through this wave's own LDS section ----
    float (*Z)[68] = reinterpret_cast<float (*)[68]>(&As[wv][0][0]);  // 4352B < 4608B section
    LGKM0();                              // fragment reads of As[wv] fully drained
#pragma unroll
    for (int h = 0; h < 2; ++h) {
#pragma unroll
        for (int n = 0; n < 4; ++n)
#pragma unroll
            for (int q = 0; q < 4; ++q)
                Z[4*lg + q][16*n + lr] = acc[h][n][q];
        LGKM0();                          // RAW: repack writes visible to reads
        if constexpr (OUTM == 0) {
            float* eout = (float*)eoutv;
#pragma unroll
            for (int it = 0; it < 4; ++it) {
                const int rr = lg + 4*it;            // 0..15
                const int b  = 16*h + rr;
                float4 z = *reinterpret_cast<float4*>(&Z[rr][lr*4]);
                *reinterpret_cast<float4*>(eout + ((size_t)b*EE + e)*DD + lr*4) = z;
            }
        } else {
            // store as next layer's A-fragments: row b=16h+rr, cols c0..c0+7
            // -> frag (m'=h, s'=(l&7)>>2), lane l' = rr + ((l&3)<<4)
            short* eoutp = (short*)eoutv + (size_t)e*BB*DD;
#pragma unroll
            for (int it = 0; it < 2; ++it) {
                const int rr = (l >> 3) + 8*it;      // 0..15
                const int c0 = (l & 7)*8;
                float4 zlo = *reinterpret_cast<float4*>(&Z[rr][c0]);
                float4 zhi = *reinterpret_cast<float4*>(&Z[rr][c0+4]);
                bf16x8 o;
                o[0]=f2bf(zlo.x); o[1]=f2bf(zlo.y); o[2]=f2bf(zlo.z); o[3]=f2bf(zlo.w);
                o[4]=f2bf(zhi.x); o[5]=f2bf(zhi.y); o[6]=f2bf(zhi.z); o[7]=f2bf(zhi.w);
                const int sp = (l & 7) >> 2;
                const int lp = rr + ((l & 3) << 4);
                *reinterpret_cast<bf16x8*>(eoutp + ((h*2 + sp)*64 + lp)*8) = o;
            }
        }
        LGKM0();                          // WAR: half-h reads done before h+1 overwrite
    }
}

// ---------------------------------------------------------------------------
// k_attn v2: per (b,i): logits = lrelu(s[j]+t[i]+u[b,i*N+j]) -> softmax over j
//   agg[b,i,:] = sum_j attn_j * zh[b,j,:]
// j-loop split into 4 independent accumulator chains (16 loads in flight).
__global__ void k_attn(const float* __restrict__ sI, const float* __restrict__ tI,
                       const float* __restrict__ u, const float* __restrict__ zh,
                       float* __restrict__ agg)
{
    int blk = blockIdx.x; int b = blk >> 7, i = blk & 127;
    int l = threadIdx.x;
    __shared__ float at[NN];
    float ti = tI[blk];
    float l0 = sI[b*NN + l]      + ti + u[b*EE + i*NN + l];
    float l1 = sI[b*NN + l + 64] + ti + u[b*EE + i*NN + l + 64];
    l0 = l0 >= 0.f ? l0 : 0.01f*l0;
    l1 = l1 >= 0.f ? l1 : 0.01f*l1;
    float mx = fmaxf(l0, l1);
#pragma unroll
    for (int off = 32; off; off >>= 1) mx = fmaxf(mx, __shfl_xor(mx, off));
    float e0 = __expf(l0 - mx), e1 = __expf(l1 - mx);
    float sm = e0 + e1;
#pragma unroll
    for (int off = 32; off; off >>= 1) sm += __shfl_xor(sm, off);
    float inv = 1.f / sm;
    at[l]      = e0 * inv;
    at[l + 64] = e1 * inv;
    __syncthreads();
    const float* zb = zh + (size_t)b*NN*DD + l;
    float a0 = 0.f, a1 = 0.f, a2 = 0.f, a3 = 0.f;
#pragma unroll 4
    for (int j = 0; j < NN; j += 4) {
        a0 += at[j]     * zb[(j)    *DD];
        a1 += at[j + 1] * zb[(j + 1)*DD];
        a2 += at[j + 2] * zb[(j + 2)*DD];
        a3 += at[j + 3] * zb[(j + 3)*DD];
    }
    agg[(b*NN + i)*DD + l] = (a0 + a1) + (a2 + a3);
}

// ---------------------------------------------------------------------------
// k_vbn: vertex BN (channel i over b,d) + residual + ELU
__global__ void k_vbn(const float* __restrict__ agg, const float* __restrict__ xres,
                      const float* __restrict__ gv, const float* __restrict__ bv,
                      float* __restrict__ xout)
{
    int i = blockIdx.x, t = threadIdx.x;
    float vals[8];
    float s1 = 0.f, s2 = 0.f;
#pragma unroll
    for (int q = 0; q < 8; ++q) {
        int m = t + 256*q; int b = m >> 6, d = m & 63;
        float v = agg[(b*NN + i)*DD + d];
        vals[q] = v; s1 += v; s2 += v*v;
    }
#pragma unroll
    for (int off = 1; off < 64; off <<= 1) {
        s1 += __shfl_xor(s1, off);
        s2 += __shfl_xor(s2, off);
    }
    __shared__ float r1[4], r2[4];
    int wv = t >> 6;
    if ((t & 63) == 0) { r1[wv] = s1; r2[wv] = s2; }
    __syncthreads();
    s1 = r1[0] + r1[1] + r1[2] + r1[3];
    s2 = r2[0] + r2[1] + r2[2] + r2[3];
    float mean  = s1 * (1.f/2048.f);
    float var   = s2 * (1.f/2048.f) - mean*mean;
    float scale = gv[i] * rsqrtf(var + EPSI);
    float shift = bv[i] - mean*scale;
#pragma unroll
    for (int q = 0; q < 8; ++q) {
        int m = t + 256*q; int b = m >> 6, d = m & 63;
        float v = vals[q]*scale + shift + xres[(b*NN + i)*DD + d];
        xout[(b*NN + i)*DD + d] = v > 0.f ? v : __expf(v) - 1.f;
    }
}

// ---------------------------------------------------------------------------
extern "C" void kernel_launch(void* const* d_in, const int* in_sizes, int n_in,
                              void* d_out, int out_size, void* d_ws, size_t ws_size,
                              hipStream_t stream)
{
    const float* x    = (const float*)d_in[0];
    const float* edge = (const float*)d_in[1];
    const float* Wh1  = (const float*)d_in[2];
    const float* We1  = (const float*)d_in[3];
    const float* Wp1  = (const float*)d_in[4];
    const float* Wa1  = (const float*)d_in[5];
    const float* Wh2  = (const float*)d_in[6];
    const float* We2  = (const float*)d_in[7];
    const float* Wp2  = (const float*)d_in[8];
    const float* Wa2  = (const float*)d_in[9];
    const float* gv1  = (const float*)d_in[10];
    const float* bv1  = (const float*)d_in[11];
    const float* ge1  = (const float*)d_in[12];
    const float* be1  = (const float*)d_in[13];
    const float* gv2  = (const float*)d_in[14];
    const float* bv2  = (const float*)d_in[15];
    const float* ge2  = (const float*)d_in[16];
    const float* be2  = (const float*)d_in[17];

    float* xout = (float*)d_out;                    // (B,N,D)
    float* eout = (float*)d_out + BB*NN*DD;         // (B,E,D) final edge output

    float* ws  = (float*)d_ws;
    short* MbT = (short*)ws;  ws += DD*DD/2;        // bf16 M fragment-major (8 KB)
    short* wfT = (short*)ws;  ws += 1024/2;         // bf16 w fragment-major (2 KB)
    float* zh  = ws;  ws += BB*NN*DD;
    float* PsT = ws;  ws += NN*BB*DD;               // fragment-layout Ps (1 MB)
    float* PdT = ws;  ws += NN*BB*DD;               // fragment-layout Pd (1 MB)
    float* sb  = ws;  ws += BB*NN;
    float* tb  = ws;  ws += BB*NN;
    float* ub  = ws;  ws += BB*EE;
    float* agg = ws;  ws += BB*NN*DD;
    float* x1  = ws;  ws += BB*NN*DD;
    short* ebf = (short*)ws;                        // A-frag-major intermediate (67 MB)
    const size_t need = ((size_t)(ws - (float*)d_ws))*4 + (size_t)EE*BB*DD*2;

    const bool dense = (ws_size >= need);

    // ----- layer 1 -----
    k_node<<<BB*NN + 64, 64, 0, stream>>>(x, Wh1, Wp1, We1, Wa1, zh, PsT, PdT, sb, tb, MbT, wfT);
    if (dense)
        k_edge<0,1><<<EE/4, 256, 0, stream>>>(edge, MbT, wfT, PsT, PdT, ge1, be1, ebf, ub);
    else
        k_edge<0,0><<<EE/4, 256, 0, stream>>>(edge, MbT, wfT, PsT, PdT, ge1, be1, eout, ub);
    k_attn<<<BB*NN, 64, 0, stream>>>(sb, tb, ub, zh, agg);
    k_vbn<<<NN, 256, 0, stream>>>(agg, x, gv1, bv1, x1);
    // ----- layer 2 -----
    k_node<<<BB*NN + 64, 64, 0, stream>>>(x1, Wh2, Wp2, We2, Wa2, zh, PsT, PdT, sb, tb, MbT, wfT);
    if (dense)
        k_edge<1,0><<<EE/4, 256, 0, stream>>>(ebf, MbT, wfT, PsT, PdT, ge2, be2, eout, ub);
    else  // in-place on eout: staged reads complete at __syncthreads before stores
        k_edge<0,0><<<EE/4, 256, 0, stream>>>(eout, MbT, wfT, PsT, PdT, ge2, be2, eout, ub);
    k_attn<<<BB*NN, 64, 0, stream>>>(sb, tb, ub, zh, agg);
    k_vbn<<<NN, 256, 0, stream>>>(agg, x1, gv2, bv2, xout);
}